// Round 12
// baseline (257.559 us; speedup 1.0000x reference)
//
#include <hip/hip_runtime.h>
#include <hip/hip_bf16.h>
#include <float.h>

// DensityLoss: B=4, N=8192, D=3, K=10 NN (excluding self).
// Keep 11 smallest d^2 per row (incl. self at 0), avg = sum(sqrt)/10,
// out = mean_b var_ddof1_i(avg[b,i]).
//
// R12: ZERO memory ops in the hot loop. Each wave owns 512 candidates as
// 8 chunks of 64; a chunk lives in per-lane VGPRs (lane = candidate),
// loaded coalesced once and double-buffered in registers. Candidates are
// broadcast to all lanes via v_readlane (literal lane index after unroll)
// -> SGPR operands feed the distance directly. Selection: sorted-desc
// top-11 on INTEGER bit patterns (d^2 >= 0 so float order == int order):
//   w[s] = max3( w[s+2], min(w[s+1], hi), min(w[s], lo) )
// 1024-thr blocks (16 waves), fused variance finalize.

#define N_PTS 8192
#define NB 4
#define KNN 11
#define THREADS 1024
#define WAVES 16
#define CAND_PER_WAVE (N_PTS / WAVES)    // 512
#define NCHUNK (CAND_PER_WAVE / 64)      // 8
#define MERGE_STRIDE (WAVES * KNN + 1)   // 177
#define NBLOCKS (NB * (N_PTS / 64))      // 512
#define IPOSINF 0x7F800000

__device__ __forceinline__ int imin2(int a, int b) { return a < b ? a : b; }
__device__ __forceinline__ int imax2(int a, int b) { return a > b ? a : b; }

__device__ __forceinline__ float blane(float v, int l) {
  return __int_as_float(__builtin_amdgcn_readlane(__float_as_int(v), l));
}

__device__ __forceinline__ void insert_pair_i(int* w, float da, float db) {
  const int ia = __float_as_int(da);
  const int ib = __float_as_int(db);
  const int lo = imin2(ia, ib);
  const int hi = imax2(ia, ib);
#pragma unroll
  for (int s = 0; s < KNN; ++s)
    w[s] = imax2(imax2(w[s + 2], imin2(w[s + 1], hi)), imin2(w[s], lo));
}

__global__ __launch_bounds__(THREADS, 8) void knn_fused_kernel(
    const float* __restrict__ pc, double* __restrict__ wsd,
    unsigned int* __restrict__ done_cnt, float* __restrict__ out) {
  __shared__ int sMerge[64 * MERGE_STRIDE];   // 45.3 KB

  const int b = blockIdx.x >> 7;
  const int rowBase = (blockIdx.x & 127) << 6;
  const int tid = threadIdx.x;
  const int wid = __builtin_amdgcn_readfirstlane(tid >> 6);
  const int lane = tid & 63;
  const int row = rowBase + lane;

  const float* __restrict__ batch = pc + (size_t)b * (N_PTS * 3);

  const float xi = batch[row * 3 + 0];
  const float yi = batch[row * 3 + 1];
  const float zi = batch[row * 3 + 2];

  int w[KNN + 2];
#pragma unroll
  for (int s = 0; s < KNN; ++s) w[s] = IPOSINF;
  w[KNN] = -1;
  w[KNN + 1] = -1;

  // chunk 0 load (lane = candidate within chunk), then register dbuf
  const int cbase = wid * CAND_PER_WAVE;
  float cx, cy, cz, nx, ny, nz;
  {
    const int p = (cbase + lane) * 3;
    cx = batch[p + 0]; cy = batch[p + 1]; cz = batch[p + 2];
  }
  for (int c = 0; c < NCHUNK; ++c) {
    if (c + 1 < NCHUNK) {
      const int p = (cbase + (c + 1) * 64 + lane) * 3;
      nx = batch[p + 0]; ny = batch[p + 1]; nz = batch[p + 2];
    }
#pragma unroll
    for (int l = 0; l < 64; l += 2) {
      const float ax = blane(cx, l),     ay = blane(cy, l),     az = blane(cz, l);
      const float bx = blane(cx, l + 1), by = blane(cy, l + 1), bz = blane(cz, l + 1);
      const float dax = xi - ax, day = yi - ay, daz = zi - az;
      const float dbx = xi - bx, dby = yi - by, dbz = zi - bz;
      const float d2a = fmaf(dax, dax, fmaf(day, day, daz * daz));
      const float d2b = fmaf(dbx, dbx, fmaf(dby, dby, dbz * dbz));
      insert_pair_i(w, d2a, d2b);
    }
    cx = nx; cy = ny; cz = nz;
  }

  // publish each wave's sorted top-11 per row; merge 176 -> 11
#pragma unroll
  for (int s = 0; s < KNN; ++s)
    sMerge[lane * MERGE_STRIDE + wid * KNN + s] = w[s];
  __syncthreads();

  if (tid < 64) {
    int best[KNN + 2];
#pragma unroll
    for (int s = 0; s < KNN; ++s) best[s] = IPOSINF;
    best[KNN] = -1;
    best[KNN + 1] = -1;
    const int* m = &sMerge[tid * MERGE_STRIDE];
#pragma unroll 2
    for (int c = 0; c < WAVES * KNN; c += 2) {
      const int ia = m[c];
      const int ib = m[c + 1];
      const int lo = imin2(ia, ib);
      const int hi = imax2(ia, ib);
#pragma unroll
      for (int s = 0; s < KNN; ++s)
        best[s] =
            imax2(imax2(best[s + 2], imin2(best[s + 1], hi)),
                  imin2(best[s], lo));
    }

    float sum = 0.0f;
#pragma unroll
    for (int s = 0; s < KNN; ++s) sum += sqrtf(__int_as_float(best[s]));
    const double avg = (double)(sum * (1.0f / 10.0f));

    double S = avg, S2 = avg * avg;
#pragma unroll
    for (int off = 32; off > 0; off >>= 1) {
      S += __shfl_down(S, off, 64);
      S2 += __shfl_down(S2, off, 64);
    }
    if (tid == 0) {
      atomicAdd(&wsd[2 * b + 0], S);
      atomicAdd(&wsd[2 * b + 1], S2);
    }
  }

  if (tid == 0) {
    __threadfence();
    const unsigned int old = atomicAdd(done_cnt, 1u);
    if (old == NBLOCKS - 1) {
      double total = 0.0;
#pragma unroll
      for (int bb = 0; bb < NB; ++bb) {
        const double S = atomicAdd(&wsd[2 * bb + 0], 0.0);
        const double S2 = atomicAdd(&wsd[2 * bb + 1], 0.0);
        total += (S2 - S * S / (double)N_PTS) / (double)(N_PTS - 1);
      }
      out[0] = (float)(total / NB);
    }
  }
}

extern "C" void kernel_launch(void* const* d_in, const int* in_sizes, int n_in,
                              void* d_out, int out_size, void* d_ws,
                              size_t ws_size, hipStream_t stream) {
  const float* pc = (const float*)d_in[0];
  float* out = (float*)d_out;
  double* wsd = (double*)d_ws;
  unsigned int* done_cnt = (unsigned int*)((char*)d_ws + 2 * NB * sizeof(double));

  hipMemsetAsync(d_ws, 0, 2 * NB * sizeof(double) + sizeof(unsigned int),
                 stream);
  knn_fused_kernel<<<NBLOCKS, THREADS, 0, stream>>>(pc, wsd, done_cnt, out);
}